// Round 11
// baseline (47.246 us; speedup 1.0000x reference)
//
#include <hip/hip_runtime.h>

// PatchExtractor: B=64, C=128, H=W=64, M=16, n=15. Bit-exact reformulation:
//   ix = y_cord + j - 7, iy = x_cord + i - 7   (reference swaps x/y coords)
//   valid = (0<=ix<64) && (0<=iy<64)
//   out[p][c][i][j] = valid ? x[b][c][iy][ix] : 0       for c in [0,128)
//   in_bounds (c=128) = valid minus reciprocal-multiply boundary flips:
//     flip iff idx==63 && coord<=62 (per axis)  [XLA lowers /63 -> *fl32(1/63);
//     csn error +2.0..2.2 ulp for coord 56..62 pushes grid past +1.0 at idx 63]
//
// R9: 44.9us, 185 MB/replay at 4.1 TB/s. FETCH=65.6MB despite x (134MB)
// fitting in L3 (256MB): the 116MB output write stream allocates in L3 and
// evicts half of x every replay. This version: NON-TEMPORAL stores (gfx950
// nt flag, no-allocate) so the write-once output stream stops polluting L3.
// (R10 failed to compile: __builtin_nontemporal_store rejects HIP_vector_type
// float4 -> use clang ext_vector_type(4) alias, same layout/alignment.)

constexpr int NP    = 15;
constexpr int NPOS  = NP * NP;          // 225
constexpr int CH    = 128;
constexpr int HH    = 64, WW = 64;
constexpr int PLANE = HH * WW;          // 4096
constexpr int MPB   = 16;               // patches (units) per batch
constexpr unsigned PER_PATCH = (CH + 1) * NPOS;   // 29025

typedef float f4 __attribute__((ext_vector_type(4)));

__device__ __forceinline__ float sample(const float* __restrict__ s,
                                        int xs, int ys, int pos) {
  const int i  = pos / NP;              // magic-mul
  const int j  = pos - i * NP;
  const int ix = ys + j - 7;            // x index from y_cord (reference quirk)
  const int iy = xs + i - 7;
  if (((unsigned)ix < (unsigned)WW) && ((unsigned)iy < (unsigned)HH)) {
    const int c4 = ix >> 2, w = ix & 3;
    return s[(iy << 6) + (((c4 + iy) & 15) << 2) + w];
  }
  return 0.0f;
}

__global__ __launch_bounds__(256)
void patch_nt(const float* __restrict__ x,
              const int* __restrict__ xcord,
              const int* __restrict__ ycord,
              float* __restrict__ out) {
  const int cg = blockIdx.x;            // 0..127 = channel, 128 = in_bounds
  const int b  = blockIdx.y;            // batch
  const int t  = threadIdx.x;

  __shared__ int    sx[MPB], sy[MPB];
  __shared__ float4 s4[HH * (WW / 4)];  // 16 KB plane (linear; swizzle via src)

  if (t < MPB) { sx[t] = xcord[b * MPB + t]; sy[t] = ycord[b * MPB + t]; }

  if (cg == CH) {
    // in_bounds channel: no x data needed (0.8% of work)
    __syncthreads();
    for (int e = t; e < MPB * NPOS; e += 256) {
      const int p   = e / NPOS;
      const int pos = e - p * NPOS;
      const int i  = pos / NP;
      const int j  = pos - i * NP;
      const int xs = sx[p], ys = sy[p];
      const int ix = ys + j - 7;
      const int iy = xs + i - 7;
      const bool v = ((unsigned)ix < (unsigned)WW) && ((unsigned)iy < (unsigned)HH);
      const bool xflip = (ix == WW - 1) && (ys < WW - 1);
      const bool yflip = (iy == HH - 1) && (xs < HH - 1);
      __builtin_nontemporal_store(
          (v && !xflip && !yflip) ? 1.0f : 0.0f,
          out + (size_t)(b * MPB + p) * PER_PATCH + (size_t)CH * NPOS + pos);
    }
    return;
  }

  // Phase 1: DMA one channel plane HBM->LDS (global_load_lds width=16),
  // source pre-permuted so LDS slot (row,c4') holds global col (c4'-row)&15.
  const float4* __restrict__ src =
      reinterpret_cast<const float4*>(x + ((size_t)b * CH + cg) * PLANE);
#pragma unroll
  for (int k = 0; k < 4; ++k) {
    const int slot  = k * 256 + t;            // LDS float4 slot this lane fills
    const int row   = slot >> 4;
    const int c4p   = slot & 15;
    const int srcf4 = (row << 4) + ((c4p - row) & 15);
    float4* ldsbase = &s4[k * 256 + (t & 192)];   // wave-uniform base
    __builtin_amdgcn_global_load_lds(
        (const __attribute__((address_space(1))) void*)(src + srcf4),
        (__attribute__((address_space(3))) void*)ldsbase,
        16, 0, 0);
  }
  __syncthreads();   // drains vmcnt

  // Phase 2: one wave per (patch, channel) chunk of 225 consecutive floats.
  const float* __restrict__ s = reinterpret_cast<const float*>(s4);
  const int wv   = t >> 6;              // wave 0..3
  const int lane = t & 63;
  for (int p = wv; p < MPB; p += 4) {
    const int xs = sx[p], ys = sy[p];
    const size_t Bp = (size_t)(b * MPB + p) * PER_PATCH + (size_t)cg * NPOS;
    const int h  = (4 - (int)(Bp & 3)) & 3;       // head scalars to align
    const int nq = (NPOS - h) >> 2;               // aligned float4 count (55/56)
    const int r  = NPOS - h - 4 * nq;             // tail scalars

    if (lane < h)
      __builtin_nontemporal_store(sample(s, xs, ys, lane), out + Bp + lane);

    if (lane < nq) {
      const int p0 = h + 4 * lane;
      f4 o;
      o.x = sample(s, xs, ys, p0);
      o.y = sample(s, xs, ys, p0 + 1);
      o.z = sample(s, xs, ys, p0 + 2);
      o.w = sample(s, xs, ys, p0 + 3);
      __builtin_nontemporal_store(
          o, reinterpret_cast<f4*>(out + Bp + h + 4 * (size_t)lane));
    }

    if (lane < r) {
      const int pt = h + 4 * nq + lane;
      __builtin_nontemporal_store(sample(s, xs, ys, pt), out + Bp + pt);
    }
  }
}

extern "C" void kernel_launch(void* const* d_in, const int* in_sizes, int n_in,
                              void* d_out, int out_size, void* d_ws, size_t ws_size,
                              hipStream_t stream) {
  const float* x  = (const float*)d_in[0];
  const int*   xc = (const int*)d_in[1];
  const int*   yc = (const int*)d_in[2];
  float* outp = (float*)d_out;

  dim3 grid(CH + 1, 64);   // (channel | in_bounds, batch)
  patch_nt<<<grid, 256, 0, stream>>>(x, xc, yc, outp);
}

// Round 12
// 47.043 us; speedup vs baseline: 1.0043x; 1.0043x over previous
//
#include <hip/hip_runtime.h>

// PatchExtractor: B=64, C=128, H=W=64, M=16, n=15. Bit-exact reformulation:
//   ix = y_cord + j - 7, iy = x_cord + i - 7   (reference swaps x/y coords)
//   valid = (0<=ix<64) && (0<=iy<64)
//   out[p][c][i][j] = valid ? x[b][c][iy][ix] : 0       for c in [0,128)
//   in_bounds (c=128) = valid minus reciprocal-multiply boundary flips:
//     flip iff idx==63 && coord<=62 (per axis)  [XLA lowers /63 -> *fl32(1/63);
//     csn error +2.0..2.2 ulp for coord 56..62 pushes grid past +1.0 at idx 63]
//
// R11 post-mortem: nt stores refuted (FETCH unchanged, WRITE +5MB, dur +2us)
// -- Infinity Cache is memory-side, no-allocate doesn't reach it. R9's wall:
// write stream = 900B chunks scattered 116KB apart (low DRAM page locality,
// 4.1 vs 7 TB/s fill). This version: PATCH-MAJOR blocks. Block (p, g) writes
// ONE contiguous 7.2KB span (8 channels x 225; g=15 adds in_bounds ch) and
// stages only rows [r0,r0+14] of its 8 planes (8 x 3840B contiguous) via
// global_load_lds w16 + inverse-swizzle-on-source. g = bid&15 puts each
// channel-slice on a fixed XCD -> the 16-patch re-reads of the same planes
// hit that XCD's L2.

constexpr int NP    = 15;
constexpr int NPOS  = NP * NP;          // 225
constexpr int CH    = 128;
constexpr int HH    = 64, WW = 64;
constexpr int PLANE = HH * WW;          // 4096
constexpr int CPG   = 8;                // channels per group
constexpr int NG    = CH / CPG;         // 16 groups (g=15 also does ch 128)
constexpr int ROWS  = 15;               // staged rows per channel
constexpr int CHF   = ROWS * WW;        // 960 floats per channel window
constexpr int NF4   = CPG * CHF / 4;    // 1920 staged float4 slots
constexpr unsigned PER_PATCH = (CH + 1) * NPOS;   // 29025

typedef float f4 __attribute__((ext_vector_type(4)));

__global__ __launch_bounds__(256)
void patch_pm(const float* __restrict__ x,
              const int* __restrict__ xcord,
              const int* __restrict__ ycord,
              float* __restrict__ out) {
  const int bid = blockIdx.x;
  const int g   = bid & 15;             // channel group (and XCD slice)
  const int p   = bid >> 4;             // patch id 0..1023
  const int b   = p >> 4;               // batch
  const int t   = threadIdx.x;

  const int xs = xcord[p];              // uniform -> scalar loads
  const int ys = ycord[p];
  const int r0 = min(max(xs - 7, 0), HH - ROWS);   // staged-row window start

  __shared__ float s[CPG * CHF];        // 30720 B

  // Phase 1: DMA 8 channel row-windows (each 3840B contiguous) HBM->LDS.
  // LDS slot (ch,row,c4') holds global col (c4'-row)&15 (read-swizzle inverse).
  const float4* __restrict__ src =
      reinterpret_cast<const float4*>(x) +
      ((size_t)b * CH + (size_t)g * CPG) * (PLANE / 4) + (size_t)r0 * (WW / 4);
#pragma unroll
  for (int k = 0; k < 8; ++k) {
    const int slot = k * 256 + t;       // LDS float4 slot
    if (slot < NF4) {
      const int ch  = slot / 240;       // 240 f4 per channel (magic-mul)
      const int rem = slot - ch * 240;
      const int row = rem >> 4;
      const int c4p = rem & 15;
      const int sc4 = (c4p - row) & 15;
      const float4* gsrc = src + (size_t)ch * (PLANE / 4) + row * (WW / 4) + sc4;
      float4* ldsbase = reinterpret_cast<float4*>(s) + k * 256 + (t & 192);
      __builtin_amdgcn_global_load_lds(
          (const __attribute__((address_space(1))) void*)gsrc,
          (__attribute__((address_space(3))) void*)ldsbase,
          16, 0, 0);
    }
  }
  __syncthreads();   // drains vmcnt

  // Phase 2: write the contiguous span [S, S+L) for this (patch, group).
  const unsigned S = (unsigned)p * PER_PATCH + (unsigned)g * (CPG * NPOS);
  const int L = CPG * NPOS + (g == NG - 1 ? NPOS : 0);   // 1800 or 2025

  auto samp = [&](int pos) -> float {
    const int cl  = pos / NPOS;         // local channel 0..8 (magic-mul)
    const int r2  = pos - cl * NPOS;
    const int i   = r2 / NP;            // magic-mul
    const int j   = r2 - i * NP;
    const int ix  = ys + j - 7;         // x index from y_cord (reference quirk)
    const int iy  = xs + i - 7;
    const bool v  = ((unsigned)ix < (unsigned)WW) && ((unsigned)iy < (unsigned)HH);
    if (cl == CPG) {                    // in_bounds channel (g==15 only)
      const bool xf = (ix == WW - 1) && (ys < WW - 1);
      const bool yf = (iy == HH - 1) && (xs < HH - 1);
      return (v && !xf && !yf) ? 1.0f : 0.0f;
    }
    if (!v) return 0.0f;
    const int row = iy - r0;            // 0..14 for all valid iy
    const int c4  = ix >> 2, w = ix & 3;
    return s[cl * CHF + (row << 6) + (((c4 + row) & 15) << 2) + w];
  };

  const int h  = (4 - (int)(S & 3)) & 3;   // head scalars to 16B-align
  const int nq = (L - h) >> 2;             // aligned float4 count
  const int rr = L - h - 4 * nq;           // tail scalars

  if (t < h) out[S + t] = samp(t);

  for (int q = t; q < nq; q += 256) {
    const int p0 = h + 4 * q;
    f4 o;
    o.x = samp(p0);
    o.y = samp(p0 + 1);
    o.z = samp(p0 + 2);
    o.w = samp(p0 + 3);
    *reinterpret_cast<f4*>(out + (size_t)S + h + 4 * (size_t)q) = o;
  }

  if (t < rr) {
    const int pt = h + 4 * nq + t;
    out[S + pt] = samp(pt);
  }
}

extern "C" void kernel_launch(void* const* d_in, const int* in_sizes, int n_in,
                              void* d_out, int out_size, void* d_ws, size_t ws_size,
                              hipStream_t stream) {
  const float* x  = (const float*)d_in[0];
  const int*   xc = (const int*)d_in[1];
  const int*   yc = (const int*)d_in[2];
  float* outp = (float*)d_out;

  patch_pm<<<1024 * NG, 256, 0, stream>>>(x, xc, yc, outp);
}